// Round 14
// baseline (269.110 us; speedup 1.0000x reference)
//
#include <hip/hip_runtime.h>
#include <math.h>

#define ND 20000
#define NF 50000
#define NE 400000
#define NT (NF + ND)     // combined dst space (feature first, then device)
#define NBKT 256
#define BKTW 274         // 256*274 = 70144 >= NT
// HID=128, H=8, D=16, L=2, IN=128, OUT=32

typedef __attribute__((ext_vector_type(8))) short short8;
typedef __attribute__((ext_vector_type(4))) float f32x4;
typedef unsigned short us;

static __device__ __forceinline__ us f2bf(float f) {
    unsigned u = __builtin_bit_cast(unsigned, f);
    u += 0x7FFF + ((u >> 16) & 1);          // round-to-nearest-even
    return (us)(u >> 16);
}
static __device__ __forceinline__ float bf2f(us h) {
    return __builtin_bit_cast(float, (unsigned)h << 16);
}
static __device__ __forceinline__ float bflo(unsigned u) {
    return __builtin_bit_cast(float, u << 16);
}
static __device__ __forceinline__ float bfhi(unsigned u) {
    return __builtin_bit_cast(float, u & 0xFFFF0000u);
}
static __device__ __forceinline__ float gelu_f(float x) {
    return 0.5f * x * (1.0f + erff(x * 0.70710678118654752f));
}

// ---------------------------------------------------------------------------
// FUSED bucket-histogram + weight/bias prep.
// WT[id] stored XOR-SWIZZLED: (c*128+k) ^ ((c&7)<<3).
// id 0: W_dev_in, 1: W_feat_in, 2+lt: Wq, 6+lt: WkF, 10+lt: WvF, 14+lt: Wa.
// ---------------------------------------------------------------------------
__global__ void k_hist_prep(const int* __restrict__ dA, const int* __restrict__ dB,
                            int* __restrict__ blockhist, int HB,
                            const float* __restrict__ W_dev_in, const float* __restrict__ W_feat_in,
                            const float* __restrict__ Wq, const float* __restrict__ Wk,
                            const float* __restrict__ Wv, const float* __restrict__ Wa,
                            const float* __restrict__ b_dev_in, const float* __restrict__ b_feat_in,
                            const float* __restrict__ bq, const float* __restrict__ bk,
                            const float* __restrict__ bv, const float* __restrict__ ba,
                            const float* __restrict__ a_rel, const float* __restrict__ m_rel,
                            const float* __restrict__ p_rel,
                            us* __restrict__ WT, float* __restrict__ B_all) {
    __shared__ int hist[NBKT];
    if ((int)blockIdx.x < HB) {
        hist[threadIdx.x] = 0;
        __syncthreads();
        int base_e = blockIdx.x * 4096;
        #pragma unroll
        for (int j = 0; j < 16; ++j) {
            int e = base_e + j * 256 + threadIdx.x;
            if (e < 2 * NE) {
                int g = (e < NE) ? dA[e] : (NF + dB[e - NE]);
                atomicAdd(&hist[g / BKTW], 1);
            }
        }
        __syncthreads();
        blockhist[blockIdx.x * NBKT + threadIdx.x] = hist[threadIdx.x];
        return;
    }
    int idx = (blockIdx.x - HB) * 256 + threadIdx.x;
    if (idx < 18 * 16384) {
        int k = idx & 127, c = (idx >> 7) & 127, id = idx >> 14;
        float val;
        if (id == 0) val = W_dev_in[k * 128 + c];
        else if (id == 1) val = W_feat_in[k * 128 + c];
        else if (id < 6) val = Wq[(id - 2) * 16384 + k * 128 + c];
        else if (id < 10) {
            int lt = id - 6, h = c >> 4, e = c & 15;
            const float* A = a_rel + (lt * 8 + h) * 256;
            const float* Ws = Wk + lt * 16384 + k * 128 + h * 16;
            float sm = 0.f;
            #pragma unroll
            for (int d = 0; d < 16; ++d) sm += Ws[d] * A[d * 16 + e];
            val = sm * p_rel[lt * 8 + h] * 0.25f;
        } else if (id < 14) {
            int lt = id - 10, h = c >> 4, e = c & 15;
            const float* A = m_rel + (lt * 8 + h) * 256;
            const float* Ws = Wv + lt * 16384 + k * 128 + h * 16;
            float sm = 0.f;
            #pragma unroll
            for (int d = 0; d < 16; ++d) sm += Ws[d] * A[d * 16 + e];
            val = sm;
        } else val = Wa[(id - 14) * 16384 + k * 128 + c];
        WT[(size_t)id * 16384 + (((c * 128 + k)) ^ ((c & 7) << 3))] = f2bf(val);
    } else {
        int j = idx - 18 * 16384;
        if (j >= 18 * 128) return;
        int c = j & 127, id = j >> 7;
        float v;
        if (id == 0) v = b_dev_in[c];
        else if (id == 1) v = b_feat_in[c];
        else if (id < 6) v = bq[(id - 2) * 128 + c];
        else if (id < 10) {
            int lt = id - 6, h = c >> 4, e = c & 15;
            const float* A = a_rel + (lt * 8 + h) * 256;
            const float* bs = bk + lt * 128 + h * 16;
            float sm = 0.f;
            #pragma unroll
            for (int d = 0; d < 16; ++d) sm += bs[d] * A[d * 16 + e];
            v = sm * p_rel[lt * 8 + h] * 0.25f;
        } else if (id < 14) {
            int lt = id - 10, h = c >> 4, e = c & 15;
            const float* A = m_rel + (lt * 8 + h) * 256;
            const float* bs = bv + lt * 128 + h * 16;
            float sm = 0.f;
            #pragma unroll
            for (int d = 0; d < 16; ++d) sm += bs[d] * A[d * 16 + e];
            v = sm;
        } else v = ba[(id - 14) * 128 + c];
        B_all[j] = v;
    }
}

__global__ void k_scanA(int* __restrict__ blockhist, int* __restrict__ totals, int HB) {
    __shared__ int sd[256];
    int b = blockIdx.x, t = threadIdx.x;
    int v = (t < HB) ? blockhist[t * NBKT + b] : 0;
    sd[t] = v; __syncthreads();
    for (int off = 1; off < 256; off <<= 1) {
        int add = (t >= off) ? sd[t - off] : 0;
        __syncthreads();
        sd[t] += add;
        __syncthreads();
    }
    if (t < HB) blockhist[t * NBKT + b] = sd[t] - v;
    if (t == 255) totals[b] = sd[255];
}

// scatter (src,g) into bucket-partitioned pairs; each block redundantly scans
// totals in LDS (replaces a separate scan dispatch).
__global__ void k_scatter(const int* __restrict__ sA, const int* __restrict__ dA,
                          const int* __restrict__ sB, const int* __restrict__ dB,
                          const int* __restrict__ blockhist, const int* __restrict__ totals,
                          uint2* __restrict__ pairs) {
    __shared__ int lcur[NBKT];
    __shared__ int sdb[NBKT];
    int t = threadIdx.x;
    int tv = totals[t];
    sdb[t] = tv; __syncthreads();
    for (int off = 1; off < 256; off <<= 1) {
        int add = (t >= off) ? sdb[t - off] : 0;
        __syncthreads();
        sdb[t] += add;
        __syncthreads();
    }
    lcur[t] = (sdb[t] - tv) + blockhist[blockIdx.x * NBKT + t];
    __syncthreads();
    int base_e = blockIdx.x * 4096;
    #pragma unroll
    for (int j = 0; j < 16; ++j) {
        int e = base_e + j * 256 + t;
        if (e < 2 * NE) {
            int src, g;
            if (e < NE) { src = sA[e]; g = dA[e]; }
            else        { src = sB[e - NE]; g = NF + dB[e - NE]; }
            int pos = atomicAdd(&lcur[g / BKTW], 1);
            pairs[pos] = make_uint2((unsigned)src, (unsigned)g);
        }
    }
}

__global__ void k_bucket_csr(const uint2* __restrict__ pairs, const int* __restrict__ totals,
                             int* __restrict__ rs, int* __restrict__ esrc) {
    __shared__ int cnt[BKTW];
    __shared__ int excl[BKTW];
    __shared__ int sdb[NBKT];
    __shared__ int sde[NBKT];
    int b = blockIdx.x, t = threadIdx.x;
    int tv = totals[t];
    sdb[t] = tv; __syncthreads();
    for (int off = 1; off < 256; off <<= 1) {
        int add = (t >= off) ? sdb[t - off] : 0;
        __syncthreads();
        sdb[t] += add;
        __syncthreads();
    }
    sde[t] = sdb[t] - tv;                       // exclusive base per bucket
    __syncthreads();
    int start = sde[b], end = sdb[b];
    int g0 = b * BKTW;
    for (int i = t; i < BKTW; i += 256) cnt[i] = 0;
    __syncthreads();
    for (int i = start + t; i < end; i += 256)
        atomicAdd(&cnt[(int)pairs[i].y - g0], 1);
    __syncthreads();
    if (t < 64) {
        int lane = t;
        int vals[5]; int s = 0;
        #pragma unroll
        for (int j = 0; j < 5; ++j) {
            int i = lane * 5 + j;
            vals[j] = (i < BKTW) ? cnt[i] : 0;
            s += vals[j];
        }
        int incl = s;
        #pragma unroll
        for (int off = 1; off < 64; off <<= 1) {
            int n = __shfl_up(incl, off);
            if (lane >= off) incl += n;
        }
        int run = incl - s;
        #pragma unroll
        for (int j = 0; j < 5; ++j) {
            int i = lane * 5 + j;
            if (i < BKTW) excl[i] = run;
            run += vals[j];
        }
    }
    __syncthreads();
    int nloc = min(BKTW, NT - g0);
    for (int i = t; i < nloc; i += 256) rs[g0 + i] = start + excl[i];
    if (b == NBKT - 1 && t == 0) rs[NT] = sdb[255];
    __syncthreads();
    for (int i = start + t; i < end; i += 256) {
        uint2 p = pairs[i];
        int pos = start + atomicAdd(&excl[(int)p.y - g0], 1);
        esrc[pos] = (int)p.x;
    }
}

// ---------------------------------------------------------------------------
// MFMA GEMM over BOTH node types. blockIdx.x < GB0 -> type 0 (device).
// W (32KB, pre-swizzled) staged to LDS via global_load_lds; B-fragments are
// conflict-free ds_read_b128.
// MODE 0: single plane, plain store to Y[row][128] (proj).
// MODE 1: 3 planes (q/k/v) in one block, A-frags loaded once:
//         plane 0 -> q[N][128], planes 1/2 -> kv[N][256].
// ---------------------------------------------------------------------------
template<int MODE, int AF32, int RELU>
__global__ __launch_bounds__(256) void mfma_gemm2(
    const void* __restrict__ X0, const void* __restrict__ X1,
    const us* __restrict__ WT0, const float* __restrict__ Ball,
    us* __restrict__ Y0, us* __restrict__ Y1,
    int N0, int N1, int GB0, int widbase,
    us* __restrict__ K0, us* __restrict__ K1) {
    __shared__ us Wlds[16384];                  // 32 KB, swizzled layout
    const int type = (blockIdx.x >= (unsigned)GB0) ? 1 : 0;
    const int bx = blockIdx.x - (type ? GB0 : 0);
    const int N = type ? N1 : N0;
    const void* Xv = type ? X1 : X0;
    const int NP = (MODE == 1) ? 3 : 1;

    const int lane = threadIdx.x & 63;
    const int wave = threadIdx.x >> 6;
    const int row_base = bx * 128 + wave * 32;
    const int l15 = lane & 15, lg = lane >> 4;
    const int kbase = lg * 8;

    {
        const char* gsrc = (const char*)(WT0 + (size_t)(widbase + type) * 16384)
                           + wave * 8192 + lane * 16;
        char* ldst = (char*)Wlds + wave * 8192;
        #pragma unroll
        for (int i = 0; i < 8; ++i) {
            __builtin_amdgcn_global_load_lds(
                (const __attribute__((address_space(1))) void*)(gsrc + i * 1024),
                (__attribute__((address_space(3))) void*)(ldst + i * 1024),
                16, 0, 0);
        }
    }

    short8 a[2][4];
    #pragma unroll
    for (int mf = 0; mf < 2; ++mf) {
        int r = row_base + mf * 16 + l15;
        r = r < N ? r : N - 1;
        if (AF32) {
            const float* Xf = (const float*)Xv + (size_t)r * 128;
            #pragma unroll
            for (int kf = 0; kf < 4; ++kf) {
                float4 lo = *(const float4*)(Xf + kf * 32 + kbase);
                float4 hi = *(const float4*)(Xf + kf * 32 + kbase + 4);
                short8 t;
                t[0] = (short)f2bf(lo.x); t[1] = (short)f2bf(lo.y);
                t[2] = (short)f2bf(lo.z); t[3] = (short)f2bf(lo.w);
                t[4] = (short)f2bf(hi.x); t[5] = (short)f2bf(hi.y);
                t[6] = (short)f2bf(hi.z); t[7] = (short)f2bf(hi.w);
                a[mf][kf] = t;
            }
        } else {
            const us* Xb = (const us*)Xv + (size_t)r * 128;
            #pragma unroll
            for (int kf = 0; kf < 4; ++kf)
                a[mf][kf] = *(const short8*)(Xb + kf * 32 + kbase);
        }
    }

    __syncthreads();

    const unsigned swz = (unsigned)((l15 & 7) << 4);

    for (int p = 0; p < NP; ++p) {
        const int wid = widbase + type + 4 * p;
        const float* bias = Ball + wid * 128;

        f32x4 acc[2][8];
        #pragma unroll
        for (int mf = 0; mf < 2; ++mf)
            #pragma unroll
            for (int cf = 0; cf < 8; ++cf) acc[mf][cf] = (f32x4){0.f, 0.f, 0.f, 0.f};

        #pragma unroll
        for (int cf = 0; cf < 8; ++cf) {
            const unsigned rowbyte = (unsigned)((cf * 16 + l15) * 256 + kbase * 2);
            #pragma unroll
            for (int kf = 0; kf < 4; ++kf) {
                short8 b = *(const short8*)((const char*)Wlds + ((rowbyte + kf * 64) ^ swz));
                acc[0][cf] = __builtin_amdgcn_mfma_f32_16x16x32_bf16(a[0][kf], b, acc[0][cf], 0, 0, 0);
                acc[1][cf] = __builtin_amdgcn_mfma_f32_16x16x32_bf16(a[1][kf], b, acc[1][cf], 0, 0, 0);
            }
        }

        if (MODE == 1 && p + 1 < NP) {
            __syncthreads();
            const char* gsrc = (const char*)(WT0 + (size_t)(widbase + type + 4 * (p + 1)) * 16384)
                               + wave * 8192 + lane * 16;
            char* ldst = (char*)Wlds + wave * 8192;
            #pragma unroll
            for (int i = 0; i < 8; ++i) {
                __builtin_amdgcn_global_load_lds(
                    (const __attribute__((address_space(1))) void*)(gsrc + i * 1024),
                    (__attribute__((address_space(3))) void*)(ldst + i * 1024),
                    16, 0, 0);
            }
        }

        float bval[8];
        #pragma unroll
        for (int cf = 0; cf < 8; ++cf) bval[cf] = bias[cf * 16 + l15];

        #pragma unroll
        for (int mf = 0; mf < 2; ++mf)
            #pragma unroll
            for (int r = 0; r < 4; ++r) {
                int grow = row_base + mf * 16 + lg * 4 + r;
                if (grow >= N) continue;
                #pragma unroll
                for (int cf = 0; cf < 8; ++cf) {
                    float v = acc[mf][cf][r] + bval[cf];
                    if (RELU) v = fmaxf(v, 0.f);
                    us val = f2bf(v);
                    int col = cf * 16 + l15;
                    if (MODE == 0 || p == 0) {
                        (type ? Y1 : Y0)[(size_t)grow * 128 + col] = val;
                    } else {
                        (type ? K1 : K0)[(size_t)grow * 256 + (p - 1) * 128 + col] = val;
                    }
                }
            }

        if (MODE == 1 && p + 1 < NP) __syncthreads();
    }
}

// ---------------------------------------------------------------------------
// Final head: Y[N,32](f32) = X(bf16)[N,128] @ W[128,32] + b
// ---------------------------------------------------------------------------
__global__ __launch_bounds__(256) void gemm_out_k(
    const us* __restrict__ X, const float* __restrict__ W,
    const float* __restrict__ bias, float* __restrict__ Y, int N) {
    __shared__ float Ws[128 * 32];
    __shared__ float Xs[8][128];
    const int tid = threadIdx.x;
    const int row0 = blockIdx.x * 8;
    #pragma unroll
    for (int it = 0; it < 16; ++it) Ws[it * 256 + tid] = W[it * 256 + tid];
    #pragma unroll
    for (int it = 0; it < 2; ++it) {
        int idx = it * 256 + tid;
        int rr = idx >> 6, kp = idx & 63;
        int gr = row0 + rr;
        unsigned u = (gr < N) ? *(const unsigned*)(X + (size_t)gr * 128 + kp * 2) : 0u;
        Xs[rr][kp * 2]     = bflo(u);
        Xs[rr][kp * 2 + 1] = bfhi(u);
    }
    __syncthreads();
    const int rr = tid >> 5, c = tid & 31;
    float acc = bias[c];
    #pragma unroll 8
    for (int k = 0; k < 128; ++k)
        acc = fmaf(Xs[rr][k], Ws[k * 32 + c], acc);
    int gr = row0 + rr;
    if (gr < N) Y[(size_t)gr * 32 + c] = acc;
}

// ---------------------------------------------------------------------------
// FUSED edge-aggregation + o-GEMM + skip/residual/LayerNorm.
// Block = 16 dsts of ONE type -> 4375 blocks (same wave supply as the
// unfused edge kernel; the 64-dst version starved the device at 4.3
// waves/SIMD). Phase 1: each 16-lane group owns one dst; gelu'd agg row ->
// 4 KB swizzled LDS tile. Phase 2: WAVE 0 ONLY runs the 16x128 MFMA GEMM
// (B direct from L2-hot swizzled WT) + skip/LN epilogue; waves 1-3 exit.
// ---------------------------------------------------------------------------
#define EDGE_STEP(kc, vc, pidx)                                        \
    {                                                                  \
        float part = qv[0] * bflo(kc.x);                               \
        part = fmaf(qv[1], bfhi(kc.x), part);                          \
        part = fmaf(qv[2], bflo(kc.y), part);                          \
        part = fmaf(qv[3], bfhi(kc.y), part);                          \
        part = fmaf(qv[4], bflo(kc.z), part);                          \
        part = fmaf(qv[5], bfhi(kc.z), part);                          \
        part = fmaf(qv[6], bflo(kc.w), part);                          \
        part = fmaf(qv[7], bfhi(kc.w), part);                          \
        part += __shfl_xor(part, 1);                                   \
        float w = ((pidx) < p1) ? __expf(part) : 0.f;                  \
        s += w;                                                        \
        a[0] = fmaf(w, bflo(vc.x), a[0]);                              \
        a[1] = fmaf(w, bfhi(vc.x), a[1]);                              \
        a[2] = fmaf(w, bflo(vc.y), a[2]);                              \
        a[3] = fmaf(w, bfhi(vc.y), a[3]);                              \
        a[4] = fmaf(w, bflo(vc.z), a[4]);                              \
        a[5] = fmaf(w, bfhi(vc.z), a[5]);                              \
        a[6] = fmaf(w, bflo(vc.w), a[6]);                              \
        a[7] = fmaf(w, bfhi(vc.w), a[7]);                              \
    }

__global__ __launch_bounds__(256) void edge_fused(
    const us* __restrict__ q_d, const us* __restrict__ q_f,
    const us* __restrict__ kv_d, const us* __restrict__ kv_f,
    const int* __restrict__ rs, const int* __restrict__ esrc,
    const us* __restrict__ WT0, const float* __restrict__ Ball, int widbase,
    us* __restrict__ xd, us* __restrict__ xf,
    const float* __restrict__ skipv, const float* __restrict__ lng,
    const float* __restrict__ lnb, int GB0) {
    __shared__ us Alds[2048];                   // 4 KB agg tile [16][128]
    const int type = (blockIdx.x >= (unsigned)GB0) ? 1 : 0;   // 0=device
    const int bx = blockIdx.x - (type ? GB0 : 0);
    const int N = type ? NF : ND;
    const us* q  = type ? q_f : q_d;
    const us* kv = type ? kv_d : kv_f;          // dsts gather the OTHER type's kv
    us* xw = type ? xf : xd;
    const int goff = type ? 0 : NF;
    const int row0 = bx * 16;
    const int wid = widbase + type;
    const us* WTg = WT0 + (size_t)wid * 16384;  // swizzled Wa (L2-hot)

    const int t = threadIdx.x;
    const int lane = t & 63;
    const int wave = t >> 6;
    const int l15 = lane & 15, lg = lane >> 4;
    const int kbase = lg * 8;
    const int li = t & 15;

    // ---- phase 1: each 16-lane group aggregates one dst
    {
        int dst_local = t >> 4;                 // 0..15
        int dst = row0 + dst_local;
        unsigned o0 = 0, o1 = 0, o2 = 0, o3 = 0;
        if (dst < N) {
            int g = dst + goff;
            uint4 qb = *(const uint4*)(q + (size_t)dst * 128 + li * 8);
            float qv[8];
            qv[0] = bflo(qb.x); qv[1] = bfhi(qb.x);
            qv[2] = bflo(qb.y); qv[3] = bfhi(qb.y);
            qv[4] = bflo(qb.z); qv[5] = bfhi(qb.z);
            qv[6] = bflo(qb.w); qv[7] = bfhi(qb.w);

            const int p0 = rs[g], p1 = rs[g + 1];
            float s = 0.f;
            float a[8];
            #pragma unroll
            for (int j = 0; j < 8; ++j) a[j] = 0.f;

            const size_t loff = (size_t)li * 8;
            if (p0 < p1) {
                const int last = p1 - 1;
                uint4 kA0, vA0, kA1, vA1, kB0, vB0, kB1, vB1;
                int sN0, sN1, sN2, sN3;
                int s0 = esrc[p0], s1 = esrc[min(p0 + 1, last)];
                int s2 = esrc[min(p0 + 2, last)], s3 = esrc[min(p0 + 3, last)];
                kA0 = *(const uint4*)(kv + (size_t)s0 * 256 + loff);
                vA0 = *(const uint4*)(kv + (size_t)s0 * 256 + 128 + loff);
                kA1 = *(const uint4*)(kv + (size_t)s1 * 256 + loff);
                vA1 = *(const uint4*)(kv + (size_t)s1 * 256 + 128 + loff);
                kB0 = *(const uint4*)(kv + (size_t)s2 * 256 + loff);
                vB0 = *(const uint4*)(kv + (size_t)s2 * 256 + 128 + loff);
                kB1 = *(const uint4*)(kv + (size_t)s3 * 256 + loff);
                vB1 = *(const uint4*)(kv + (size_t)s3 * 256 + 128 + loff);
                sN0 = esrc[min(p0 + 4, last)];
                sN1 = esrc[min(p0 + 5, last)];
                sN2 = esrc[min(p0 + 6, last)];
                sN3 = esrc[min(p0 + 7, last)];

                for (int p = p0; p < p1; p += 4) {
                    EDGE_STEP(kA0, vA0, p);
                    EDGE_STEP(kA1, vA1, p + 1);
                    kA0 = *(const uint4*)(kv + (size_t)sN0 * 256 + loff);
                    vA0 = *(const uint4*)(kv + (size_t)sN0 * 256 + 128 + loff);
                    kA1 = *(const uint4*)(kv + (size_t)sN1 * 256 + loff);
                    vA1 = *(const uint4*)(kv + (size_t)sN1 * 256 + 128 + loff);
                    sN0 = esrc[min(p + 8, last)];
                    sN1 = esrc[min(p + 9, last)];
                    EDGE_STEP(kB0, vB0, p + 2);
                    EDGE_STEP(kB1, vB1, p + 3);
                    kB0 = *(const uint4*)(kv + (size_t)sN2 * 256 + loff);
                    vB0 = *(const uint4*)(kv + (size_t)sN2 * 256 + 128 + loff);
                    kB1 = *(const uint4*)(kv + (size_t)sN3 * 256 + loff);
                    vB1 = *(const uint4*)(kv + (size_t)sN3 * 256 + 128 + loff);
                    sN2 = esrc[min(p + 10, last)];
                    sN3 = esrc[min(p + 11, last)];
                }
            }
            float r = 1.0f / (s + 1e-16f);
            us lo, hi;
            lo = f2bf(gelu_f(a[0] * r)); hi = f2bf(gelu_f(a[1] * r));
            o0 = (unsigned)lo | ((unsigned)hi << 16);
            lo = f2bf(gelu_f(a[2] * r)); hi = f2bf(gelu_f(a[3] * r));
            o1 = (unsigned)lo | ((unsigned)hi << 16);
            lo = f2bf(gelu_f(a[4] * r)); hi = f2bf(gelu_f(a[5] * r));
            o2 = (unsigned)lo | ((unsigned)hi << 16);
            lo = f2bf(gelu_f(a[6] * r)); hi = f2bf(gelu_f(a[7] * r));
            o3 = (unsigned)lo | ((unsigned)hi << 16);
        }
        unsigned byteoff = ((unsigned)(dst_local * 256 + li * 16)) ^ ((unsigned)(dst_local & 7) << 4);
        *(uint4*)((char*)Alds + byteoff) = make_uint4(o0, o1, o2, o3);
    }

    __syncthreads();                            // agg tile complete

    if (wave != 0) return;                      // GEMM phase: wave 0 only

    // ---- phase 2: 16x128 GEMM (A from LDS, B direct from L2) + LN epilogue
    short8 av[4];
    {
        unsigned rb = (unsigned)(l15 * 256);
        unsigned sx = (unsigned)((l15 & 7) << 4);
        #pragma unroll
        for (int kf = 0; kf < 4; ++kf)
            av[kf] = *(const short8*)((const char*)Alds + ((rb + kf * 64 + lg * 16) ^ sx));
    }

    const unsigned swzu = (unsigned)((l15 & 7) << 3);   // us-index XOR
    f32x4 acc[8];
    #pragma unroll
    for (int cf = 0; cf < 8; ++cf) acc[cf] = (f32x4){0.f, 0.f, 0.f, 0.f};
    #pragma unroll
    for (int cf = 0; cf < 8; ++cf) {
        const unsigned rowus = (unsigned)((cf * 16 + l15) * 128 + kbase);
        #pragma unroll
        for (int kf = 0; kf < 4; ++kf) {
            short8 b = *(const short8*)(WTg + ((rowus + kf * 32) ^ swzu));
            acc[cf] = __builtin_amdgcn_mfma_f32_16x16x32_bf16(av[kf], b, acc[cf], 0, 0, 0);
        }
    }

    const int lt = widbase - 14 + type;         // = l*2 + type
    float sk = 1.f / (1.f + __expf(-skipv[lt]));
    float bval[8], gv[8], bv2[8];
    #pragma unroll
    for (int cf = 0; cf < 8; ++cf) {
        bval[cf] = Ball[wid * 128 + cf * 16 + l15];
        gv[cf]   = lng[(size_t)lt * 128 + cf * 16 + l15];
        bv2[cf]  = lnb[(size_t)lt * 128 + cf * 16 + l15];
    }
    #pragma unroll
    for (int r = 0; r < 4; ++r) {
        int grow = row0 + lg * 4 + r;           // uniform across shfl-16 group
        if (grow >= N) continue;
        float tt[8];
        float sum = 0.f;
        #pragma unroll
        for (int cf = 0; cf < 8; ++cf) {
            float o = acc[cf][r] + bval[cf];
            float x = bf2f(xw[(size_t)grow * 128 + cf * 16 + l15]);
            tt[cf] = (2.f - sk) * x + sk * o;
            sum += tt[cf];
        }
        sum += __shfl_xor(sum, 1); sum += __shfl_xor(sum, 2);
        sum += __shfl_xor(sum, 4); sum += __shfl_xor(sum, 8);
        float mean = sum * (1.0f / 128.0f);
        float vs = 0.f;
        #pragma unroll
        for (int cf = 0; cf < 8; ++cf) { tt[cf] -= mean; vs += tt[cf] * tt[cf]; }
        vs += __shfl_xor(vs, 1); vs += __shfl_xor(vs, 2);
        vs += __shfl_xor(vs, 4); vs += __shfl_xor(vs, 8);
        float inv = rsqrtf(vs * (1.0f / 128.0f) + 1e-5f);
        #pragma unroll
        for (int cf = 0; cf < 8; ++cf)
            xw[(size_t)grow * 128 + cf * 16 + l15] = f2bf(tt[cf] * inv * gv[cf] + bv2[cf]);
    }
}

// ---------------------------------------------------------------------------
extern "C" void kernel_launch(void* const* d_in, const int* in_sizes, int n_in,
                              void* d_out, int out_size, void* d_ws, size_t ws_size,
                              hipStream_t stream) {
    const float* x_device = (const float*)d_in[0];
    const float* x_feature = (const float*)d_in[1];
    const int* e_df_src = (const int*)d_in[2];
    const int* e_df_dst = (const int*)d_in[3];
    const int* e_fd_src = (const int*)d_in[4];
    const int* e_fd_dst = (const int*)d_in[5];
    const float* W_dev_in = (const float*)d_in[6];
    const float* b_dev_in = (const float*)d_in[7];
    const float* W_feat_in = (const float*)d_in[8];
    const float* b_feat_in = (const float*)d_in[9];
    const float* Wk = (const float*)d_in[10];
    const float* bk = (const float*)d_in[11];
    const float* Wq = (const float*)d_in[12];
    const float* bq = (const float*)d_in[13];
    const float* Wv = (const float*)d_in[14];
    const float* bv = (const float*)d_in[15];
    const float* a_rel = (const float*)d_in[16];
    const float* m_rel = (const float*)d_in[17];
    const float* p_rel = (const float*)d_in[18];
    const float* Wa = (const float*)d_in[19];
    const float* ba = (const float*)d_in[20];
    const float* skip = (const float*)d_in[21];
    const float* ln_g = (const float*)d_in[22];
    const float* ln_b = (const float*)d_in[23];
    const float* W_out = (const float*)d_in[24];
    const float* b_out = (const float*)d_in[25];

    char* ws = (char*)d_ws;
    size_t off = 0;
    auto alloc = [&](size_t bytes) -> void* {
        void* p = ws + off;
        off = (off + bytes + 255) & ~(size_t)255;
        return p;
    };
    us* xd     = (us*)alloc((size_t)ND * 128 * 2);
    us* xf     = (us*)alloc((size_t)NF * 128 * 2);
    us* q_d    = (us*)alloc((size_t)ND * 128 * 2);
    us* q_f    = (us*)alloc((size_t)NF * 128 * 2);
    us* kv_d   = (us*)alloc((size_t)ND * 256 * 2);
    us* kv_f   = (us*)alloc((size_t)NF * 256 * 2);
    us* WT     = (us*)alloc((size_t)18 * 16384 * 2);
    float* B_all = (float*)alloc(18 * 128 * 4);
    int* rs     = (int*)alloc((size_t)(NT + 1) * 4);
    int* esrc   = (int*)alloc((size_t)(2 * NE + 8) * 4);
    uint2* pairs = (uint2*)alloc((size_t)2 * NE * 8);
    int* blockhist = (int*)alloc((size_t)200 * NBKT * 4);
    int* totals = (int*)alloc(NBKT * 4);

    const int HB = (2 * NE + 4095) / 4096;                 // 196
    const int PB = (18 * 16384 + 18 * 128 + 255) / 256;

    // ---- bucket-sort CSR build + weight prep (fused histogram)
    k_hist_prep<<<HB + PB, 256, 0, stream>>>(
        e_df_dst, e_fd_dst, blockhist, HB,
        W_dev_in, W_feat_in, Wq, Wk, Wv, Wa,
        b_dev_in, b_feat_in, bq, bk, bv, ba,
        a_rel, m_rel, p_rel, WT, B_all);
    k_scanA<<<NBKT, 256, 0, stream>>>(blockhist, totals, HB);
    k_scatter<<<HB, 256, 0, stream>>>(e_df_src, e_df_dst, e_fd_src, e_fd_dst,
                                      blockhist, totals, pairs);
    k_bucket_csr<<<NBKT, 256, 0, stream>>>(pairs, totals, rs, esrc);

    const int GBD = (ND + 127) / 128, GBF = (NF + 127) / 128;
    const int GBD16 = (ND + 15) / 16, GBF16 = (NF + 15) / 16;

    // ---- input projections + relu (fp32 in, bf16 out), both types fused
    mfma_gemm2<0, 1, 1><<<GBD + GBF, 256, 0, stream>>>(
        x_device, x_feature, WT, B_all, xd, xf, ND, NF, GBD, 0,
        nullptr, nullptr);

    for (int l = 0; l < 2; ++l) {
        // fused q/k/v both types, 3 planes per block (A loaded once)
        mfma_gemm2<1, 0, 0><<<GBD + GBF, 256, 0, stream>>>(
            xd, xf, WT, B_all, q_d, q_f, ND, NF, GBD, 2 + l * 2,
            kv_d, kv_f);

        // fused: edge agg (16 dsts/block, device blocks first) + o-GEMM + LN
        edge_fused<<<GBD16 + GBF16, 256, 0, stream>>>(
            q_d, q_f, kv_d, kv_f, rs, esrc, WT, B_all, 14 + l * 2,
            xd, xf, skip, ln_g, ln_b, GBD16);
    }

    gemm_out_k<<<(ND + 7) / 8, 256, 0, stream>>>(xd, W_out, b_out, (float*)d_out, ND);
}

// Round 15
// 256.525 us; speedup vs baseline: 1.0491x; 1.0491x over previous
//
#include <hip/hip_runtime.h>
#include <math.h>

#define ND 20000
#define NF 50000
#define NE 400000
#define NT (NF + ND)     // combined dst space (feature first, then device)
#define NBKT 256
#define BKTW 274         // 256*274 = 70144 >= NT
// HID=128, H=8, D=16, L=2, IN=128, OUT=32

typedef __attribute__((ext_vector_type(8))) short short8;
typedef __attribute__((ext_vector_type(4))) float f32x4;
typedef __attribute__((ext_vector_type(2))) float f32x2;
typedef unsigned short us;
typedef unsigned char u8;

static __device__ __forceinline__ us f2bf(float f) {
    unsigned u = __builtin_bit_cast(unsigned, f);
    u += 0x7FFF + ((u >> 16) & 1);          // round-to-nearest-even
    return (us)(u >> 16);
}
static __device__ __forceinline__ float bf2f(us h) {
    return __builtin_bit_cast(float, (unsigned)h << 16);
}
static __device__ __forceinline__ float bflo(unsigned u) {
    return __builtin_bit_cast(float, u << 16);
}
static __device__ __forceinline__ float bfhi(unsigned u) {
    return __builtin_bit_cast(float, u & 0xFFFF0000u);
}
static __device__ __forceinline__ float gelu_f(float x) {
    return 0.5f * x * (1.0f + erff(x * 0.70710678118654752f));
}

// f32 -> OCP e4m3fn, round-to-nearest-even, clamp to +-448 (matches gfx950
// HW fp8 format used by v_cvt_pk_f32_fp8 on the decode side).
static __device__ __forceinline__ u8 f2fp8(float f) {
    unsigned u = __builtin_bit_cast(unsigned, f);
    unsigned s = (u >> 24) & 0x80u;
    unsigned a = u & 0x7FFFFFFFu;
    if (a >= 0x43E00000u) return (u8)(s | 0x7Eu);        // >=448 (or NaN) -> 448
    if (a < 0x3C800000u) {                               // < 2^-6: subnormal
        float af = __builtin_bit_cast(float, a);
        unsigned q = (unsigned)(af * 512.0f + 0.5f);     // 0..8 (8 == 2^-6)
        return (u8)(s | q);
    }
    unsigned r = a + 0x7FFFFu + ((a >> 20) & 1u);        // RNE at 3-bit mantissa
    unsigned e8 = (r >> 23) - 120u;
    unsigned m3 = (r >> 20) & 7u;
    return (u8)(s | (e8 << 3) | m3);
}

// ---------------------------------------------------------------------------
// FUSED bucket-histogram + weight/bias prep.
// WT[id] stored XOR-SWIZZLED: (c*128+k) ^ ((c&7)<<3).
// id 0: W_dev_in, 1: W_feat_in, 2+lt: Wq, 6+lt: WkF, 10+lt: WvF, 14+lt: Wa.
// ---------------------------------------------------------------------------
__global__ void k_hist_prep(const int* __restrict__ dA, const int* __restrict__ dB,
                            int* __restrict__ blockhist, int HB,
                            const float* __restrict__ W_dev_in, const float* __restrict__ W_feat_in,
                            const float* __restrict__ Wq, const float* __restrict__ Wk,
                            const float* __restrict__ Wv, const float* __restrict__ Wa,
                            const float* __restrict__ b_dev_in, const float* __restrict__ b_feat_in,
                            const float* __restrict__ bq, const float* __restrict__ bk,
                            const float* __restrict__ bv, const float* __restrict__ ba,
                            const float* __restrict__ a_rel, const float* __restrict__ m_rel,
                            const float* __restrict__ p_rel,
                            us* __restrict__ WT, float* __restrict__ B_all) {
    __shared__ int hist[NBKT];
    if ((int)blockIdx.x < HB) {
        hist[threadIdx.x] = 0;
        __syncthreads();
        int base_e = blockIdx.x * 4096;
        #pragma unroll
        for (int j = 0; j < 16; ++j) {
            int e = base_e + j * 256 + threadIdx.x;
            if (e < 2 * NE) {
                int g = (e < NE) ? dA[e] : (NF + dB[e - NE]);
                atomicAdd(&hist[g / BKTW], 1);
            }
        }
        __syncthreads();
        blockhist[blockIdx.x * NBKT + threadIdx.x] = hist[threadIdx.x];
        return;
    }
    int idx = (blockIdx.x - HB) * 256 + threadIdx.x;
    if (idx < 18 * 16384) {
        int k = idx & 127, c = (idx >> 7) & 127, id = idx >> 14;
        float val;
        if (id == 0) val = W_dev_in[k * 128 + c];
        else if (id == 1) val = W_feat_in[k * 128 + c];
        else if (id < 6) val = Wq[(id - 2) * 16384 + k * 128 + c];
        else if (id < 10) {
            int lt = id - 6, h = c >> 4, e = c & 15;
            const float* A = a_rel + (lt * 8 + h) * 256;
            const float* Ws = Wk + lt * 16384 + k * 128 + h * 16;
            float sm = 0.f;
            #pragma unroll
            for (int d = 0; d < 16; ++d) sm += Ws[d] * A[d * 16 + e];
            val = sm * p_rel[lt * 8 + h] * 0.25f;
        } else if (id < 14) {
            int lt = id - 10, h = c >> 4, e = c & 15;
            const float* A = m_rel + (lt * 8 + h) * 256;
            const float* Ws = Wv + lt * 16384 + k * 128 + h * 16;
            float sm = 0.f;
            #pragma unroll
            for (int d = 0; d < 16; ++d) sm += Ws[d] * A[d * 16 + e];
            val = sm;
        } else val = Wa[(id - 14) * 16384 + k * 128 + c];
        WT[(size_t)id * 16384 + (((c * 128 + k)) ^ ((c & 7) << 3))] = f2bf(val);
    } else {
        int j = idx - 18 * 16384;
        if (j >= 18 * 128) return;
        int c = j & 127, id = j >> 7;
        float v;
        if (id == 0) v = b_dev_in[c];
        else if (id == 1) v = b_feat_in[c];
        else if (id < 6) v = bq[(id - 2) * 128 + c];
        else if (id < 10) {
            int lt = id - 6, h = c >> 4, e = c & 15;
            const float* A = a_rel + (lt * 8 + h) * 256;
            const float* bs = bk + lt * 128 + h * 16;
            float sm = 0.f;
            #pragma unroll
            for (int d = 0; d < 16; ++d) sm += bs[d] * A[d * 16 + e];
            v = sm * p_rel[lt * 8 + h] * 0.25f;
        } else if (id < 14) {
            int lt = id - 10, h = c >> 4, e = c & 15;
            const float* A = m_rel + (lt * 8 + h) * 256;
            const float* bs = bv + lt * 128 + h * 16;
            float sm = 0.f;
            #pragma unroll
            for (int d = 0; d < 16; ++d) sm += bs[d] * A[d * 16 + e];
            v = sm;
        } else v = ba[(id - 14) * 128 + c];
        B_all[j] = v;
    }
}

__global__ void k_scanA(int* __restrict__ blockhist, int* __restrict__ totals, int HB) {
    __shared__ int sd[256];
    int b = blockIdx.x, t = threadIdx.x;
    int v = (t < HB) ? blockhist[t * NBKT + b] : 0;
    sd[t] = v; __syncthreads();
    for (int off = 1; off < 256; off <<= 1) {
        int add = (t >= off) ? sd[t - off] : 0;
        __syncthreads();
        sd[t] += add;
        __syncthreads();
    }
    if (t < HB) blockhist[t * NBKT + b] = sd[t] - v;
    if (t == 255) totals[b] = sd[255];
}

// scatter (src,g) into bucket-partitioned pairs; each block redundantly scans
// totals in LDS (no separate scan dispatch).
__global__ void k_scatter(const int* __restrict__ sA, const int* __restrict__ dA,
                          const int* __restrict__ sB, const int* __restrict__ dB,
                          const int* __restrict__ blockhist, const int* __restrict__ totals,
                          uint2* __restrict__ pairs) {
    __shared__ int lcur[NBKT];
    __shared__ int sdb[NBKT];
    int t = threadIdx.x;
    int tv = totals[t];
    sdb[t] = tv; __syncthreads();
    for (int off = 1; off < 256; off <<= 1) {
        int add = (t >= off) ? sdb[t - off] : 0;
        __syncthreads();
        sdb[t] += add;
        __syncthreads();
    }
    lcur[t] = (sdb[t] - tv) + blockhist[blockIdx.x * NBKT + t];
    __syncthreads();
    int base_e = blockIdx.x * 4096;
    #pragma unroll
    for (int j = 0; j < 16; ++j) {
        int e = base_e + j * 256 + t;
        if (e < 2 * NE) {
            int src, g;
            if (e < NE) { src = sA[e]; g = dA[e]; }
            else        { src = sB[e - NE]; g = NF + dB[e - NE]; }
            int pos = atomicAdd(&lcur[g / BKTW], 1);
            pairs[pos] = make_uint2((unsigned)src, (unsigned)g);
        }
    }
}

__global__ void k_bucket_csr(const uint2* __restrict__ pairs, const int* __restrict__ totals,
                             int* __restrict__ rs, int* __restrict__ esrc) {
    __shared__ int cnt[BKTW];
    __shared__ int excl[BKTW];
    __shared__ int sdb[NBKT];
    __shared__ int sde[NBKT];
    int b = blockIdx.x, t = threadIdx.x;
    int tv = totals[t];
    sdb[t] = tv; __syncthreads();
    for (int off = 1; off < 256; off <<= 1) {
        int add = (t >= off) ? sdb[t - off] : 0;
        __syncthreads();
        sdb[t] += add;
        __syncthreads();
    }
    sde[t] = sdb[t] - tv;                       // exclusive base per bucket
    __syncthreads();
    int start = sde[b], end = sdb[b];
    int g0 = b * BKTW;
    for (int i = t; i < BKTW; i += 256) cnt[i] = 0;
    __syncthreads();
    for (int i = start + t; i < end; i += 256)
        atomicAdd(&cnt[(int)pairs[i].y - g0], 1);
    __syncthreads();
    if (t < 64) {
        int lane = t;
        int vals[5]; int s = 0;
        #pragma unroll
        for (int j = 0; j < 5; ++j) {
            int i = lane * 5 + j;
            vals[j] = (i < BKTW) ? cnt[i] : 0;
            s += vals[j];
        }
        int incl = s;
        #pragma unroll
        for (int off = 1; off < 64; off <<= 1) {
            int n = __shfl_up(incl, off);
            if (lane >= off) incl += n;
        }
        int run = incl - s;
        #pragma unroll
        for (int j = 0; j < 5; ++j) {
            int i = lane * 5 + j;
            if (i < BKTW) excl[i] = run;
            run += vals[j];
        }
    }
    __syncthreads();
    int nloc = min(BKTW, NT - g0);
    for (int i = t; i < nloc; i += 256) rs[g0 + i] = start + excl[i];
    if (b == NBKT - 1 && t == 0) rs[NT] = sdb[255];
    __syncthreads();
    for (int i = start + t; i < end; i += 256) {
        uint2 p = pairs[i];
        int pos = start + atomicAdd(&excl[(int)p.y - g0], 1);
        esrc[pos] = (int)p.x;
    }
}

// ---------------------------------------------------------------------------
// MFMA GEMM over BOTH node types. blockIdx.x < GB0 -> type 0 (device).
// W (32KB, pre-swizzled) staged to LDS via global_load_lds; B-fragments are
// conflict-free ds_read_b128.
// MODE 0: single plane, plain store to Y[row][128] (proj).
// MODE 1: 3 planes (q/k/v) in one block, A-frags loaded once:
//         plane 0 -> q[N][128] bf16, plane 1 -> kt[N][128] bf16,
//         plane 2 -> v8[N][128] fp8 e4m3fn (halves edge-gather V traffic).
// MODE 2: single plane + fused skip+residual+LayerNorm in place on x(K0/K1).
// ---------------------------------------------------------------------------
template<int MODE, int AF32, int RELU>
__global__ __launch_bounds__(256) void mfma_gemm2(
    const void* __restrict__ X0, const void* __restrict__ X1,
    const us* __restrict__ WT0, const float* __restrict__ Ball,
    us* __restrict__ Y0, us* __restrict__ Y1,
    int N0, int N1, int GB0, int widbase,
    us* __restrict__ K0, us* __restrict__ K1,
    u8* __restrict__ V0, u8* __restrict__ V1,
    const float* __restrict__ skipv, const float* __restrict__ lng,
    const float* __restrict__ lnb) {
    __shared__ us Wlds[16384];                  // 32 KB, swizzled layout
    const int type = (blockIdx.x >= (unsigned)GB0) ? 1 : 0;
    const int bx = blockIdx.x - (type ? GB0 : 0);
    const int N = type ? N1 : N0;
    const void* Xv = type ? X1 : X0;
    const int NP = (MODE == 1) ? 3 : 1;

    const int lane = threadIdx.x & 63;
    const int wave = threadIdx.x >> 6;
    const int row_base = bx * 128 + wave * 32;
    const int l15 = lane & 15, lg = lane >> 4;
    const int kbase = lg * 8;

    {
        const char* gsrc = (const char*)(WT0 + (size_t)(widbase + type) * 16384)
                           + wave * 8192 + lane * 16;
        char* ldst = (char*)Wlds + wave * 8192;
        #pragma unroll
        for (int i = 0; i < 8; ++i) {
            __builtin_amdgcn_global_load_lds(
                (const __attribute__((address_space(1))) void*)(gsrc + i * 1024),
                (__attribute__((address_space(3))) void*)(ldst + i * 1024),
                16, 0, 0);
        }
    }

    short8 a[2][4];
    #pragma unroll
    for (int mf = 0; mf < 2; ++mf) {
        int r = row_base + mf * 16 + l15;
        r = r < N ? r : N - 1;
        if (AF32) {
            const float* Xf = (const float*)Xv + (size_t)r * 128;
            #pragma unroll
            for (int kf = 0; kf < 4; ++kf) {
                float4 lo = *(const float4*)(Xf + kf * 32 + kbase);
                float4 hi = *(const float4*)(Xf + kf * 32 + kbase + 4);
                short8 t;
                t[0] = (short)f2bf(lo.x); t[1] = (short)f2bf(lo.y);
                t[2] = (short)f2bf(lo.z); t[3] = (short)f2bf(lo.w);
                t[4] = (short)f2bf(hi.x); t[5] = (short)f2bf(hi.y);
                t[6] = (short)f2bf(hi.z); t[7] = (short)f2bf(hi.w);
                a[mf][kf] = t;
            }
        } else {
            const us* Xb = (const us*)Xv + (size_t)r * 128;
            #pragma unroll
            for (int kf = 0; kf < 4; ++kf)
                a[mf][kf] = *(const short8*)(Xb + kf * 32 + kbase);
        }
    }

    __syncthreads();

    const unsigned swz = (unsigned)((l15 & 7) << 4);

    for (int p = 0; p < NP; ++p) {
        const int wid = widbase + type + 4 * p;
        const float* bias = Ball + wid * 128;

        f32x4 acc[2][8];
        #pragma unroll
        for (int mf = 0; mf < 2; ++mf)
            #pragma unroll
            for (int cf = 0; cf < 8; ++cf) acc[mf][cf] = (f32x4){0.f, 0.f, 0.f, 0.f};

        #pragma unroll
        for (int cf = 0; cf < 8; ++cf) {
            const unsigned rowbyte = (unsigned)((cf * 16 + l15) * 256 + kbase * 2);
            #pragma unroll
            for (int kf = 0; kf < 4; ++kf) {
                short8 b = *(const short8*)((const char*)Wlds + ((rowbyte + kf * 64) ^ swz));
                acc[0][cf] = __builtin_amdgcn_mfma_f32_16x16x32_bf16(a[0][kf], b, acc[0][cf], 0, 0, 0);
                acc[1][cf] = __builtin_amdgcn_mfma_f32_16x16x32_bf16(a[1][kf], b, acc[1][cf], 0, 0, 0);
            }
        }

        if (MODE == 1 && p + 1 < NP) {
            __syncthreads();
            const char* gsrc = (const char*)(WT0 + (size_t)(widbase + type + 4 * (p + 1)) * 16384)
                               + wave * 8192 + lane * 16;
            char* ldst = (char*)Wlds + wave * 8192;
            #pragma unroll
            for (int i = 0; i < 8; ++i) {
                __builtin_amdgcn_global_load_lds(
                    (const __attribute__((address_space(1))) void*)(gsrc + i * 1024),
                    (__attribute__((address_space(3))) void*)(ldst + i * 1024),
                    16, 0, 0);
            }
        }

        float bval[8];
        #pragma unroll
        for (int cf = 0; cf < 8; ++cf) bval[cf] = bias[cf * 16 + l15];

        if (MODE == 2) {
            const int lt = widbase - 14 + type;     // = l*2 + type
            float sk = 1.f / (1.f + __expf(-skipv[lt]));
            float gv[8], bv2[8];
            #pragma unroll
            for (int cf = 0; cf < 8; ++cf) {
                gv[cf]  = lng[(size_t)lt * 128 + cf * 16 + l15];
                bv2[cf] = lnb[(size_t)lt * 128 + cf * 16 + l15];
            }
            us* xw = type ? K1 : K0;
            #pragma unroll
            for (int mf = 0; mf < 2; ++mf)
                #pragma unroll
                for (int r = 0; r < 4; ++r) {
                    int grow = row_base + mf * 16 + lg * 4 + r;  // uniform in shfl-16 group
                    if (grow >= N) continue;
                    float t[8];
                    float sum = 0.f;
                    #pragma unroll
                    for (int cf = 0; cf < 8; ++cf) {
                        float o = acc[mf][cf][r] + bval[cf];
                        float x = bf2f(xw[(size_t)grow * 128 + cf * 16 + l15]);
                        t[cf] = (2.f - sk) * x + sk * o;
                        sum += t[cf];
                    }
                    sum += __shfl_xor(sum, 1); sum += __shfl_xor(sum, 2);
                    sum += __shfl_xor(sum, 4); sum += __shfl_xor(sum, 8);
                    float mean = sum * (1.0f / 128.0f);
                    float vs = 0.f;
                    #pragma unroll
                    for (int cf = 0; cf < 8; ++cf) { t[cf] -= mean; vs += t[cf] * t[cf]; }
                    vs += __shfl_xor(vs, 1); vs += __shfl_xor(vs, 2);
                    vs += __shfl_xor(vs, 4); vs += __shfl_xor(vs, 8);
                    float inv = rsqrtf(vs * (1.0f / 128.0f) + 1e-5f);
                    #pragma unroll
                    for (int cf = 0; cf < 8; ++cf)
                        xw[(size_t)grow * 128 + cf * 16 + l15] = f2bf(t[cf] * inv * gv[cf] + bv2[cf]);
                }
        } else {
            #pragma unroll
            for (int mf = 0; mf < 2; ++mf)
                #pragma unroll
                for (int r = 0; r < 4; ++r) {
                    int grow = row_base + mf * 16 + lg * 4 + r;
                    if (grow >= N) continue;
                    #pragma unroll
                    for (int cf = 0; cf < 8; ++cf) {
                        float v = acc[mf][cf][r] + bval[cf];
                        if (RELU) v = fmaxf(v, 0.f);
                        int col = cf * 16 + l15;
                        if (MODE == 0 || p == 0) {
                            (type ? Y1 : Y0)[(size_t)grow * 128 + col] = f2bf(v);
                        } else if (p == 1) {
                            (type ? K1 : K0)[(size_t)grow * 128 + col] = f2bf(v);
                        } else {
                            (type ? V1 : V0)[(size_t)grow * 128 + col] = f2fp8(v);
                        }
                    }
                }
        }

        if (MODE == 1 && p + 1 < NP) __syncthreads();
    }
}

// ---------------------------------------------------------------------------
// Final head: Y[N,32](f32) = X(bf16)[N,128] @ W[128,32] + b
// ---------------------------------------------------------------------------
__global__ __launch_bounds__(256) void gemm_out_k(
    const us* __restrict__ X, const float* __restrict__ W,
    const float* __restrict__ bias, float* __restrict__ Y, int N) {
    __shared__ float Ws[128 * 32];
    __shared__ float Xs[8][128];
    const int tid = threadIdx.x;
    const int row0 = blockIdx.x * 8;
    #pragma unroll
    for (int it = 0; it < 16; ++it) Ws[it * 256 + tid] = W[it * 256 + tid];
    #pragma unroll
    for (int it = 0; it < 2; ++it) {
        int idx = it * 256 + tid;
        int rr = idx >> 6, kp = idx & 63;
        int gr = row0 + rr;
        unsigned u = (gr < N) ? *(const unsigned*)(X + (size_t)gr * 128 + kp * 2) : 0u;
        Xs[rr][kp * 2]     = bflo(u);
        Xs[rr][kp * 2 + 1] = bfhi(u);
    }
    __syncthreads();
    const int rr = tid >> 5, c = tid & 31;
    float acc = bias[c];
    #pragma unroll 8
    for (int k = 0; k < 128; ++k)
        acc = fmaf(Xs[rr][k], Ws[k * 32 + c], acc);
    int gr = row0 + rr;
    if (gr < N) Y[(size_t)gr * 32 + c] = acc;
}

// ---------------------------------------------------------------------------
// Edge aggregation, BOTH edge types in one dispatch (unfused form: waves
// retire independently -> best measured). 16 lanes per dst; lane li owns
// dims [li*8, li*8+8). K gathered as bf16 (16B/lane), V as fp8 e4m3fn
// (8B/lane, HW v_cvt_pk_f32_fp8 decode) -> 384B/edge vs 512B.
// No-max softmax. Depth-2x2 software pipeline, clamped loads, masked exp.
// ---------------------------------------------------------------------------
#define EDGE_STEP(kc, vc, pidx)                                        \
    {                                                                  \
        float part = qv[0] * bflo(kc.x);                               \
        part = fmaf(qv[1], bfhi(kc.x), part);                          \
        part = fmaf(qv[2], bflo(kc.y), part);                          \
        part = fmaf(qv[3], bfhi(kc.y), part);                          \
        part = fmaf(qv[4], bflo(kc.z), part);                          \
        part = fmaf(qv[5], bfhi(kc.z), part);                          \
        part = fmaf(qv[6], bflo(kc.w), part);                          \
        part = fmaf(qv[7], bfhi(kc.w), part);                          \
        part += __shfl_xor(part, 1);                                   \
        float w = ((pidx) < p1) ? __expf(part) : 0.f;                  \
        s += w;                                                        \
        f32x2 v01 = __builtin_amdgcn_cvt_pk_f32_fp8((int)vc.x, false); \
        f32x2 v23 = __builtin_amdgcn_cvt_pk_f32_fp8((int)vc.x, true);  \
        f32x2 v45 = __builtin_amdgcn_cvt_pk_f32_fp8((int)vc.y, false); \
        f32x2 v67 = __builtin_amdgcn_cvt_pk_f32_fp8((int)vc.y, true);  \
        a[0] = fmaf(w, v01.x, a[0]);                                   \
        a[1] = fmaf(w, v01.y, a[1]);                                   \
        a[2] = fmaf(w, v23.x, a[2]);                                   \
        a[3] = fmaf(w, v23.y, a[3]);                                   \
        a[4] = fmaf(w, v45.x, a[4]);                                   \
        a[5] = fmaf(w, v45.y, a[5]);                                   \
        a[6] = fmaf(w, v67.x, a[6]);                                   \
        a[7] = fmaf(w, v67.y, a[7]);                                   \
    }

__global__ __launch_bounds__(256) void edge_agg6(
    const us* __restrict__ qf, const us* __restrict__ qd,
    const us* __restrict__ ktf, const us* __restrict__ ktd,
    const u8* __restrict__ v8f, const u8* __restrict__ v8d,
    const int* __restrict__ rs, const int* __restrict__ esrc,
    us* __restrict__ aggf, us* __restrict__ aggd) {
    int g = (blockIdx.x * 256 + threadIdx.x) >> 4;
    int li = threadIdx.x & 15;
    if (g >= NT) return;
    const us *q, *kt; const u8* v8; us* agg; int dst;
    if (g < NF) { dst = g;      q = qf; kt = ktd; v8 = v8d; agg = aggf; }
    else        { dst = g - NF; q = qd; kt = ktf; v8 = v8f; agg = aggd; }

    uint4 qb = *(const uint4*)(q + (size_t)dst * 128 + li * 8);
    float qv[8];
    qv[0] = bflo(qb.x); qv[1] = bfhi(qb.x);
    qv[2] = bflo(qb.y); qv[3] = bfhi(qb.y);
    qv[4] = bflo(qb.z); qv[5] = bfhi(qb.z);
    qv[6] = bflo(qb.w); qv[7] = bfhi(qb.w);

    const int p0 = rs[g], p1 = rs[g + 1];
    float s = 0.f;
    float a[8];
    #pragma unroll
    for (int j = 0; j < 8; ++j) a[j] = 0.f;

    const size_t loff = (size_t)li * 8;
    uint4 kA0, kA1, kB0, kB1;
    uint2 vA0, vA1, vB0, vB1;
    int sN0, sN1, sN2, sN3;

    if (p0 < p1) {
        const int last = p1 - 1;
        int s0 = esrc[p0], s1 = esrc[min(p0 + 1, last)];
        int s2 = esrc[min(p0 + 2, last)], s3 = esrc[min(p0 + 3, last)];
        kA0 = *(const uint4*)(kt + (size_t)s0 * 128 + loff);
        vA0 = *(const uint2*)(v8 + (size_t)s0 * 128 + loff);
        kA1 = *(const uint4*)(kt + (size_t)s1 * 128 + loff);
        vA1 = *(const uint2*)(v8 + (size_t)s1 * 128 + loff);
        kB0 = *(const uint4*)(kt + (size_t)s2 * 128 + loff);
        vB0 = *(const uint2*)(v8 + (size_t)s2 * 128 + loff);
        kB1 = *(const uint4*)(kt + (size_t)s3 * 128 + loff);
        vB1 = *(const uint2*)(v8 + (size_t)s3 * 128 + loff);
        sN0 = esrc[min(p0 + 4, last)];
        sN1 = esrc[min(p0 + 5, last)];
        sN2 = esrc[min(p0 + 6, last)];
        sN3 = esrc[min(p0 + 7, last)];

        for (int p = p0; p < p1; p += 4) {
            const int lastc = last;
            EDGE_STEP(kA0, vA0, p);
            EDGE_STEP(kA1, vA1, p + 1);
            kA0 = *(const uint4*)(kt + (size_t)sN0 * 128 + loff);
            vA0 = *(const uint2*)(v8 + (size_t)sN0 * 128 + loff);
            kA1 = *(const uint4*)(kt + (size_t)sN1 * 128 + loff);
            vA1 = *(const uint2*)(v8 + (size_t)sN1 * 128 + loff);
            sN0 = esrc[min(p + 8, lastc)];
            sN1 = esrc[min(p + 9, lastc)];
            EDGE_STEP(kB0, vB0, p + 2);
            EDGE_STEP(kB1, vB1, p + 3);
            kB0 = *(const uint4*)(kt + (size_t)sN2 * 128 + loff);
            vB0 = *(const uint2*)(v8 + (size_t)sN2 * 128 + loff);
            kB1 = *(const uint4*)(kt + (size_t)sN3 * 128 + loff);
            vB1 = *(const uint2*)(v8 + (size_t)sN3 * 128 + loff);
            sN2 = esrc[min(p + 10, lastc)];
            sN3 = esrc[min(p + 11, lastc)];
        }
    }

    float r = 1.0f / (s + 1e-16f);
    unsigned o[4];
    #pragma unroll
    for (int j = 0; j < 4; ++j) {
        us lo = f2bf(gelu_f(a[2 * j] * r));
        us hi = f2bf(gelu_f(a[2 * j + 1] * r));
        o[j] = (unsigned)lo | ((unsigned)hi << 16);
    }
    *(uint4*)(agg + (size_t)dst * 128 + li * 8) = make_uint4(o[0], o[1], o[2], o[3]);
}

// ---------------------------------------------------------------------------
extern "C" void kernel_launch(void* const* d_in, const int* in_sizes, int n_in,
                              void* d_out, int out_size, void* d_ws, size_t ws_size,
                              hipStream_t stream) {
    const float* x_device = (const float*)d_in[0];
    const float* x_feature = (const float*)d_in[1];
    const int* e_df_src = (const int*)d_in[2];
    const int* e_df_dst = (const int*)d_in[3];
    const int* e_fd_src = (const int*)d_in[4];
    const int* e_fd_dst = (const int*)d_in[5];
    const float* W_dev_in = (const float*)d_in[6];
    const float* b_dev_in = (const float*)d_in[7];
    const float* W_feat_in = (const float*)d_in[8];
    const float* b_feat_in = (const float*)d_in[9];
    const float* Wk = (const float*)d_in[10];
    const float* bk = (const float*)d_in[11];
    const float* Wq = (const float*)d_in[12];
    const float* bq = (const float*)d_in[13];
    const float* Wv = (const float*)d_in[14];
    const float* bv = (const float*)d_in[15];
    const float* a_rel = (const float*)d_in[16];
    const float* m_rel = (const float*)d_in[17];
    const float* p_rel = (const float*)d_in[18];
    const float* Wa = (const float*)d_in[19];
    const float* ba = (const float*)d_in[20];
    const float* skip = (const float*)d_in[21];
    const float* ln_g = (const float*)d_in[22];
    const float* ln_b = (const float*)d_in[23];
    const float* W_out = (const float*)d_in[24];
    const float* b_out = (const float*)d_in[25];

    char* ws = (char*)d_ws;
    size_t off = 0;
    auto alloc = [&](size_t bytes) -> void* {
        void* p = ws + off;
        off = (off + bytes + 255) & ~(size_t)255;
        return p;
    };
    us* xd     = (us*)alloc((size_t)ND * 128 * 2);
    us* xf     = (us*)alloc((size_t)NF * 128 * 2);
    us* q_d    = (us*)alloc((size_t)ND * 128 * 2);
    us* q_f    = (us*)alloc((size_t)NF * 128 * 2);
    us* kt_d   = (us*)alloc((size_t)ND * 128 * 2);
    us* kt_f   = (us*)alloc((size_t)NF * 128 * 2);
    u8* v8_d   = (u8*)alloc((size_t)ND * 128);
    u8* v8_f   = (u8*)alloc((size_t)NF * 128);
    us* agg_d  = (us*)alloc((size_t)ND * 128 * 2);
    us* agg_f  = (us*)alloc((size_t)NF * 128 * 2);
    us* WT     = (us*)alloc((size_t)18 * 16384 * 2);
    float* B_all = (float*)alloc(18 * 128 * 4);
    int* rs     = (int*)alloc((size_t)(NT + 1) * 4);
    int* esrc   = (int*)alloc((size_t)(2 * NE + 8) * 4);   // +8 pad for clamped prefetch
    uint2* pairs = (uint2*)alloc((size_t)2 * NE * 8);
    int* blockhist = (int*)alloc((size_t)200 * NBKT * 4);
    int* totals = (int*)alloc(NBKT * 4);

    const int HB = (2 * NE + 4095) / 4096;                 // 196
    const int PB = (18 * 16384 + 18 * 128 + 255) / 256;

    // ---- bucket-sort CSR build + weight prep (fused histogram)
    k_hist_prep<<<HB + PB, 256, 0, stream>>>(
        e_df_dst, e_fd_dst, blockhist, HB,
        W_dev_in, W_feat_in, Wq, Wk, Wv, Wa,
        b_dev_in, b_feat_in, bq, bk, bv, ba,
        a_rel, m_rel, p_rel, WT, B_all);
    k_scanA<<<NBKT, 256, 0, stream>>>(blockhist, totals, HB);
    k_scatter<<<HB, 256, 0, stream>>>(e_df_src, e_df_dst, e_fd_src, e_fd_dst,
                                      blockhist, totals, pairs);
    k_bucket_csr<<<NBKT, 256, 0, stream>>>(pairs, totals, rs, esrc);

    const int GBD = (ND + 127) / 128, GBF = (NF + 127) / 128;

    // ---- input projections + relu (fp32 in, bf16 out), both types fused
    mfma_gemm2<0, 1, 1><<<GBD + GBF, 256, 0, stream>>>(
        x_device, x_feature, WT, B_all, xd, xf, ND, NF, GBD, 0,
        nullptr, nullptr, nullptr, nullptr, nullptr, nullptr, nullptr);

    for (int l = 0; l < 2; ++l) {
        // fused q/k/v both types, 3 planes per block (A loaded once):
        // q bf16, kt bf16, v8 fp8
        mfma_gemm2<1, 0, 0><<<GBD + GBF, 256, 0, stream>>>(
            xd, xf, WT, B_all, q_d, q_f, ND, NF, GBD, 2 + l * 2,
            kt_d, kt_f, v8_d, v8_f, nullptr, nullptr, nullptr);

        // both edge types, K bf16 + V fp8 gather
        edge_agg6<<<((NT * 16) + 255) / 256, 256, 0, stream>>>(
            q_f, q_d, kt_f, kt_d, v8_f, v8_d, rs, esrc, agg_f, agg_d);

        // o = gelu(agg) @ Wa + ba, fused skip+residual+LN, in place on x
        mfma_gemm2<2, 0, 0><<<GBD + GBF, 256, 0, stream>>>(
            agg_d, agg_f, WT, B_all, nullptr, nullptr, ND, NF, GBD, 14 + l * 2,
            xd, xf, nullptr, nullptr, skip, ln_g, ln_b);
    }

    gemm_out_k<<<(ND + 7) / 8, 256, 0, stream>>>(xd, W_out, b_out, (float*)d_out, ND);
}